// Round 12
// baseline (487.235 us; speedup 1.0000x reference)
//
#include <hip/hip_runtime.h>
#include <cstdint>
#include <cstddef>

#define NN 50000
#define EE 800000
#define ETOT 850000   // EE + NN self loops
#define NEG_SLOPE 0.2f

typedef _Float16 f16;
typedef __attribute__((ext_vector_type(8))) _Float16 f16x8;
typedef __attribute__((ext_vector_type(4))) float f32x4;
typedef unsigned short u16;

__device__ __forceinline__ float leaky(float v) { return v > 0.f ? v : NEG_SLOPE * v; }

// ---------------- CSR: 3-kernel wide scan (round-9 verified) ----------------

__global__ __launch_bounds__(256) void scan1_kernel(const int* __restrict__ deg, int* __restrict__ offs,
                                                    int* __restrict__ bsum, int n) {
    __shared__ int sh[256];
    int i = blockIdx.x * 256 + threadIdx.x;
    int v = (i < n) ? deg[i] : 0;
    sh[threadIdx.x] = v;
    __syncthreads();
    for (int off = 1; off < 256; off <<= 1) {
        int t = (threadIdx.x >= off) ? sh[threadIdx.x - off] : 0;
        __syncthreads();
        sh[threadIdx.x] += t;
        __syncthreads();
    }
    if (i < n) offs[i] = sh[threadIdx.x] - v;   // exclusive within block
    if (threadIdx.x == 255) bsum[blockIdx.x] = sh[255];
}

__global__ __launch_bounds__(256) void scan2_kernel(int* __restrict__ bsum, int nb) {
    __shared__ int sh[256];
    int v = (threadIdx.x < nb) ? bsum[threadIdx.x] : 0;
    sh[threadIdx.x] = v;
    __syncthreads();
    for (int off = 1; off < 256; off <<= 1) {
        int t = (threadIdx.x >= off) ? sh[threadIdx.x - off] : 0;
        __syncthreads();
        sh[threadIdx.x] += t;
        __syncthreads();
    }
    if (threadIdx.x < nb) bsum[threadIdx.x] = sh[threadIdx.x] - v;  // exclusive
}

__global__ __launch_bounds__(256) void scan3_kernel(const int* __restrict__ bsum, int* __restrict__ offs,
                                                    int* __restrict__ cursor, int n) {
    int i = blockIdx.x * 256 + threadIdx.x;
    if (i < n) {
        int o = offs[i] + bsum[blockIdx.x];
        offs[i] = o;
        cursor[i] = o;
    }
}

// ---------------- pack weights (f16+transpose) + deg tail ----------------

__global__ __launch_bounds__(256) void packw_deg_kernel(
    const float* __restrict__ W1, const float* __restrict__ W2,
    const float* __restrict__ Wm, const float* __restrict__ Ws,
    const float* __restrict__ ams, const float* __restrict__ ass,
    const float* __restrict__ amd, const float* __restrict__ asd,
    f16* __restrict__ Wt1, f16* __restrict__ Wt2, f16* __restrict__ Wtms,
    float* __restrict__ aS, float* __restrict__ aD,
    const int* __restrict__ ei, int* __restrict__ deg) {
    int b = blockIdx.x;
    if (b >= 256) {   // deg tail
        int e = (b - 256) * 256 + threadIdx.x;
        if (e >= ETOT) return;
        int d = (e < EE) ? ei[EE + e] : (e - EE);
        atomicAdd(&deg[d], 1);
        return;
    }
    int i = b * 256 + threadIdx.x;
    {
        int n = i >> 8, k = i & 255;   // Wt[n][k] = W[k][n]
        Wt1[(size_t)n * 256 + k] = (f16)W1[(size_t)k * 256 + n];
        Wt2[(size_t)n * 256 + k] = (f16)W2[(size_t)k * 256 + n];
    }
    if (i < 4096) {
        int c = i >> 6, k = i & 63;
        float v = (c < 32) ? Wm[k * 32 + c] : Ws[k * 32 + (c - 32)];
        Wtms[(size_t)c * 64 + k] = (f16)v;
    }
    if (i < 64) {
        aS[i] = (i < 32) ? ams[i] : ass[i - 32];
        aD[i] = (i < 32) ? amd[i] : asd[i - 32];
    }
}

// ---------------- MFMA GEMM + fused score dots + tail (fill or alpha) ----------------
// TAILMODE: 0 = none, 1 = CSR fill (u16 csrc), 2 = 4-head alpha writer (previous layer).

template<int K, int NH, bool AF32, int TAILMODE>
__global__ __launch_bounds__(256) void mfma_gemm_fused(
    const void* __restrict__ Ap, const f16* __restrict__ Bt, f16* __restrict__ C,
    const float* __restrict__ aS, const float* __restrict__ aD,
    float* __restrict__ es, float* __restrict__ edi, int M, int N, int RB,
    const int* __restrict__ ei, const float* __restrict__ esA,
    const float* __restrict__ ediA, float* __restrict__ awA,
    int* __restrict__ tcur, u16* __restrict__ tcsrc) {
    if ((int)blockIdx.y >= RB) {
        int e = (((int)blockIdx.y - RB) * (int)gridDim.x + (int)blockIdx.x) * 256 + (int)threadIdx.x;
        if (e >= ETOT) return;
        int s, d;
        if (e < EE) { s = ei[e]; d = ei[EE + e]; } else { s = e - EE; d = e - EE; }
        if constexpr (TAILMODE == 1) {
            int p = atomicAdd(&tcur[d], 1);
            tcsrc[p] = (u16)s;
        } else if constexpr (TAILMODE == 2) {
            float4 esv = *(const float4*)(esA + (size_t)s * 4);
            float4 edv = *(const float4*)(ediA + (size_t)d * 8);
            float4 iv  = *(const float4*)(ediA + (size_t)d * 8 + 4);
            float4 r;
            r.x = __expf(leaky(esv.x + edv.x)) * iv.x;
            r.y = __expf(leaky(esv.y + edv.y)) * iv.y;
            r.z = __expf(leaky(esv.z + edv.z)) * iv.z;
            r.w = __expf(leaky(esv.w + edv.w)) * iv.w;
            *(float4*)(awA + (size_t)e * 4) = r;
        }
        return;
    }
    int w = threadIdx.x >> 6, lane = threadIdx.x & 63;
    int m0 = blockIdx.y * 128 + w * 32;
    int n0 = blockIdx.x * 64;
    int r = lane & 15, kb = lane >> 4;
    int ar0 = m0 + r;       if (ar0 > M - 1) ar0 = M - 1;
    int ar1 = m0 + 16 + r;  if (ar1 > M - 1) ar1 = M - 1;
    f32x4 acc[2][4] = {};
    const float* Af = (const float*)Ap;
    const f16*   Ah = (const f16*)Ap;
    size_t a0off = (size_t)ar0 * K + kb * 8;
    size_t a1off = (size_t)ar1 * K + kb * 8;
    const f16* bbase = Bt + (size_t)(n0 + r) * K + kb * 8;
    for (int k0 = 0; k0 < K; k0 += 32) {
        f16x8 a0, a1;
        if constexpr (AF32) {
            float4 l0 = *(const float4*)(Af + a0off + k0);
            float4 h0 = *(const float4*)(Af + a0off + k0 + 4);
            float4 l1 = *(const float4*)(Af + a1off + k0);
            float4 h1 = *(const float4*)(Af + a1off + k0 + 4);
            a0[0]=(f16)l0.x; a0[1]=(f16)l0.y; a0[2]=(f16)l0.z; a0[3]=(f16)l0.w;
            a0[4]=(f16)h0.x; a0[5]=(f16)h0.y; a0[6]=(f16)h0.z; a0[7]=(f16)h0.w;
            a1[0]=(f16)l1.x; a1[1]=(f16)l1.y; a1[2]=(f16)l1.z; a1[3]=(f16)l1.w;
            a1[4]=(f16)h1.x; a1[5]=(f16)h1.y; a1[6]=(f16)h1.z; a1[7]=(f16)h1.w;
        } else {
            a0 = *(const f16x8*)(Ah + a0off + k0);
            a1 = *(const f16x8*)(Ah + a1off + k0);
        }
#pragma unroll
        for (int ni = 0; ni < 4; ++ni) {
            f16x8 b = *(const f16x8*)(bbase + (size_t)ni * 16 * K + k0);
            acc[0][ni] = __builtin_amdgcn_mfma_f32_16x16x32_f16(a0, b, acc[0][ni], 0, 0, 0);
            acc[1][ni] = __builtin_amdgcn_mfma_f32_16x16x32_f16(a1, b, acc[1][ni], 0, 0, 0);
        }
    }
    float aSl[4], aDl[4];
#pragma unroll
    for (int ni = 0; ni < 4; ++ni) {
        aSl[ni] = aS[n0 + ni * 16 + r];
        aDl[ni] = aD[n0 + ni * 16 + r];
    }
#pragma unroll
    for (int mi = 0; mi < 2; ++mi) {
#pragma unroll
        for (int i = 0; i < 4; ++i) {
            int row = m0 + mi * 16 + kb * 4 + i;
            bool ok = row < M;
            if (ok) {
#pragma unroll
                for (int ni = 0; ni < 4; ++ni)
                    C[(size_t)row * N + n0 + ni * 16 + r] = (f16)acc[mi][ni][i];
            }
            if constexpr (NH == 4) {
                float pes = acc[mi][0][i] * aSl[0] + acc[mi][1][i] * aSl[1] + acc[mi][2][i] * aSl[2] + acc[mi][3][i] * aSl[3];
                float ped = acc[mi][0][i] * aDl[0] + acc[mi][1][i] * aDl[1] + acc[mi][2][i] * aDl[2] + acc[mi][3][i] * aDl[3];
#pragma unroll
                for (int off = 1; off < 16; off <<= 1) {
                    pes += __shfl_xor(pes, off);
                    ped += __shfl_xor(ped, off);
                }
                if (r == 0 && ok) {
                    es[(size_t)row * 4 + blockIdx.x] = pes;
                    edi[(size_t)row * 8 + blockIdx.x] = ped;
                }
            } else {
                float p0s = acc[mi][0][i] * aSl[0] + acc[mi][1][i] * aSl[1];
                float p1s = acc[mi][2][i] * aSl[2] + acc[mi][3][i] * aSl[3];
                float p0d = acc[mi][0][i] * aDl[0] + acc[mi][1][i] * aDl[1];
                float p1d = acc[mi][2][i] * aDl[2] + acc[mi][3][i] * aDl[3];
#pragma unroll
                for (int off = 1; off < 16; off <<= 1) {
                    p0s += __shfl_xor(p0s, off);
                    p1s += __shfl_xor(p1s, off);
                    p0d += __shfl_xor(p0d, off);
                    p1d += __shfl_xor(p1d, off);
                }
                if (r == 0 && ok) {
                    es[(size_t)row * 2 + 0] = p0s;
                    es[(size_t)row * 2 + 1] = p1s;
                    edi[(size_t)row * 4 + 0] = p0d;
                    edi[(size_t)row * 4 + 1] = p1d;
                }
            }
        }
    }
}

// ---------------- mean/log_std alpha writer ----------------

__global__ __launch_bounds__(256) void alpha_ms_kernel(const int* __restrict__ ei, const float* __restrict__ es,
                                                       const float* __restrict__ edi,
                                                       float* __restrict__ awm, float* __restrict__ aws) {
    int e = blockIdx.x * 256 + threadIdx.x;
    if (e >= ETOT) return;
    int s, d;
    if (e < EE) { s = ei[e]; d = ei[EE + e]; } else { s = e - EE; d = e - EE; }
    float2 esv = *(const float2*)(es + (size_t)s * 2);
    float2 edv = *(const float2*)(edi + (size_t)d * 4);
    float2 iv  = *(const float2*)(edi + (size_t)d * 4 + 2);
    awm[e] = __expf(leaky(esv.x + edv.x)) * iv.x;
    aws[e] = __expf(leaky(esv.y + edv.y)) * iv.y;
}

// ---------------- layer-1 aggregation: 1 node per 64-thread block ----------------

__global__ __launch_bounds__(64) void agg_concat_kernel(
    const f16* __restrict__ H, const float* __restrict__ es, float* __restrict__ edi,
    const int* __restrict__ offs, const u16* __restrict__ csrc,
    const float* __restrict__ bias, f16* __restrict__ out) {
    int lane = threadIdx.x;
    int n = blockIdx.x;
    int start = offs[n];
    int end = (n + 1 < NN) ? offs[n + 1] : ETOT;
    int deg = end - start;
    int h16 = lane >> 4, sub = lane & 15;
    float edh = edi[(size_t)n * 8 + h16];
    float dsum = 0.f;
    for (int j = sub; j < deg; j += 16) {
        int s = csrc[start + j];
        dsum += __expf(leaky(es[s * 4 + h16] + edh));
    }
    for (int off = 1; off < 16; off <<= 1) dsum += __shfl_xor(dsum, off);
    float inv = 1.f / (dsum + 1e-16f);
    if (sub == 0) edi[(size_t)n * 8 + 4 + h16] = inv;
    int half = lane >> 5;
    int l5 = lane & 31;
    int hh = l5 >> 3;
    int c8 = l5 * 8;
    float invh = __shfl(inv, hh << 4);
    float edhh = __shfl(edh, hh << 4);
    float accv[8] = {};
    int j = half;
    for (; j + 6 < deg; j += 8) {
        int p0 = start + j, p1 = start + j + 2, p2 = start + j + 4, p3 = start + j + 6;
        int s0 = csrc[p0], s1 = csrc[p1], s2 = csrc[p2], s3 = csrc[p3];
        float a0 = __expf(leaky(es[s0 * 4 + hh] + edhh)) * invh;
        float a1 = __expf(leaky(es[s1 * 4 + hh] + edhh)) * invh;
        float a2 = __expf(leaky(es[s2 * 4 + hh] + edhh)) * invh;
        float a3 = __expf(leaky(es[s3 * 4 + hh] + edhh)) * invh;
        f16x8 v0 = *(const f16x8*)(H + (size_t)s0 * 256 + c8);
        f16x8 v1 = *(const f16x8*)(H + (size_t)s1 * 256 + c8);
        f16x8 v2 = *(const f16x8*)(H + (size_t)s2 * 256 + c8);
        f16x8 v3 = *(const f16x8*)(H + (size_t)s3 * 256 + c8);
#pragma unroll
        for (int k = 0; k < 8; ++k)
            accv[k] += a0 * (float)v0[k] + a1 * (float)v1[k] + a2 * (float)v2[k] + a3 * (float)v3[k];
    }
    for (; j < deg; j += 2) {
        int s0 = csrc[start + j];
        float a0 = __expf(leaky(es[s0 * 4 + hh] + edhh)) * invh;
        f16x8 v0 = *(const f16x8*)(H + (size_t)s0 * 256 + c8);
#pragma unroll
        for (int k = 0; k < 8; ++k) accv[k] += a0 * (float)v0[k];
    }
#pragma unroll
    for (int k = 0; k < 8; ++k) accv[k] += __shfl_xor(accv[k], 32);
    if (lane < 32) {
        f16x8 r;
#pragma unroll
        for (int k = 0; k < 8; ++k) r[k] = (f16)fmaxf(accv[k] + bias[c8 + k], 0.f);
        *(f16x8*)(out + (size_t)n * 256 + c8) = r;
    }
}

// ---------------- layer-2 aggregation (mean over 4 heads) ----------------

__global__ __launch_bounds__(64) void agg_mean_kernel(
    const f16* __restrict__ H, const float* __restrict__ es, float* __restrict__ edi,
    const int* __restrict__ offs, const u16* __restrict__ csrc,
    const float* __restrict__ bias, f16* __restrict__ out) {
    int lane = threadIdx.x;
    int n = blockIdx.x;
    int start = offs[n];
    int end = (n + 1 < NN) ? offs[n + 1] : ETOT;
    int deg = end - start;
    int h16 = lane >> 4, sub = lane & 15;
    float edh = edi[(size_t)n * 8 + h16];
    float dsum = 0.f;
    for (int j = sub; j < deg; j += 16) {
        int s = csrc[start + j];
        dsum += __expf(leaky(es[s * 4 + h16] + edh));
    }
    for (int off = 1; off < 16; off <<= 1) dsum += __shfl_xor(dsum, off);
    float inv = 1.f / (dsum + 1e-16f);
    if (sub == 0) edi[(size_t)n * 8 + 4 + h16] = inv;
    int half = lane >> 5;
    int l5 = lane & 31;
    int hh = l5 >> 3;
    int c8 = l5 * 8;
    float invh = __shfl(inv, hh << 4);
    float edhh = __shfl(edh, hh << 4);
    float accv[8] = {};
    int j = half;
    for (; j + 6 < deg; j += 8) {
        int p0 = start + j, p1 = start + j + 2, p2 = start + j + 4, p3 = start + j + 6;
        int s0 = csrc[p0], s1 = csrc[p1], s2 = csrc[p2], s3 = csrc[p3];
        float a0 = __expf(leaky(es[s0 * 4 + hh] + edhh)) * invh;
        float a1 = __expf(leaky(es[s1 * 4 + hh] + edhh)) * invh;
        float a2 = __expf(leaky(es[s2 * 4 + hh] + edhh)) * invh;
        float a3 = __expf(leaky(es[s3 * 4 + hh] + edhh)) * invh;
        f16x8 v0 = *(const f16x8*)(H + (size_t)s0 * 256 + c8);
        f16x8 v1 = *(const f16x8*)(H + (size_t)s1 * 256 + c8);
        f16x8 v2 = *(const f16x8*)(H + (size_t)s2 * 256 + c8);
        f16x8 v3 = *(const f16x8*)(H + (size_t)s3 * 256 + c8);
#pragma unroll
        for (int k = 0; k < 8; ++k)
            accv[k] += a0 * (float)v0[k] + a1 * (float)v1[k] + a2 * (float)v2[k] + a3 * (float)v3[k];
    }
    for (; j < deg; j += 2) {
        int s0 = csrc[start + j];
        float a0 = __expf(leaky(es[s0 * 4 + hh] + edhh)) * invh;
        f16x8 v0 = *(const f16x8*)(H + (size_t)s0 * 256 + c8);
#pragma unroll
        for (int k = 0; k < 8; ++k) accv[k] += a0 * (float)v0[k];
    }
#pragma unroll
    for (int k = 0; k < 8; ++k) {
        accv[k] += __shfl_xor(accv[k], 8);
        accv[k] += __shfl_xor(accv[k], 16);
        accv[k] += __shfl_xor(accv[k], 32);
    }
    if (lane < 8) {
        f16x8 r;
#pragma unroll
        for (int k = 0; k < 8; ++k) r[k] = (f16)fmaxf(accv[k] * 0.25f + bias[lane * 8 + k], 0.f);
        *(f16x8*)(out + (size_t)n * 64 + lane * 8) = r;
    }
}

// ---------------- mean/log_std heads aggregation ----------------

__global__ __launch_bounds__(64) void agg_ms_kernel(
    const f16* __restrict__ H, const float* __restrict__ es, float* __restrict__ edi,
    const int* __restrict__ offs, const u16* __restrict__ csrc,
    const float* __restrict__ bm, const float* __restrict__ bs,
    float* __restrict__ zmean, float* __restrict__ zlog) {
    int lane = threadIdx.x;
    int n = blockIdx.x;
    int start = offs[n];
    int end = (n + 1 < NN) ? offs[n + 1] : ETOT;
    int deg = end - start;
    int g = lane >> 5, sub = lane & 31;
    float edg = edi[(size_t)n * 4 + g];
    float dsum = 0.f;
    for (int j = sub; j < deg; j += 32) {
        int s = csrc[start + j];
        dsum += __expf(leaky(es[s * 2 + g] + edg));
    }
    for (int off = 1; off < 32; off <<= 1) dsum += __shfl_xor(dsum, off);
    float inv = 1.f / (dsum + 1e-16f);
    if (sub == 0) edi[(size_t)n * 4 + 2 + g] = inv;
    int slot = lane >> 3;
    int le = lane & 7;
    int g2 = le >> 2;
    int c8 = le * 8;
    float invg = __shfl(inv, g2 << 5);
    float edg2 = __shfl(edg, g2 << 5);
    float accv[8] = {};
    for (int j = slot; j < deg; j += 8) {
        int p = start + j;
        int s = csrc[p];
        float a = __expf(leaky(es[s * 2 + g2] + edg2)) * invg;
        f16x8 v = *(const f16x8*)(H + (size_t)s * 64 + c8);
#pragma unroll
        for (int k = 0; k < 8; ++k) accv[k] += a * (float)v[k];
    }
#pragma unroll
    for (int k = 0; k < 8; ++k) {
        accv[k] += __shfl_xor(accv[k], 8);
        accv[k] += __shfl_xor(accv[k], 16);
        accv[k] += __shfl_xor(accv[k], 32);
    }
    if (lane < 4) {
        float4 r0, r1;
        int cb = lane * 8;
        r0.x = accv[0] + bm[cb + 0]; r0.y = accv[1] + bm[cb + 1];
        r0.z = accv[2] + bm[cb + 2]; r0.w = accv[3] + bm[cb + 3];
        r1.x = accv[4] + bm[cb + 4]; r1.y = accv[5] + bm[cb + 5];
        r1.z = accv[6] + bm[cb + 6]; r1.w = accv[7] + bm[cb + 7];
        *(float4*)(zmean + (size_t)n * 32 + cb) = r0;
        *(float4*)(zmean + (size_t)n * 32 + cb + 4) = r1;
    } else if (lane < 8) {
        float4 r0, r1;
        int cb = (lane - 4) * 8;
        r0.x = accv[0] + bs[cb + 0]; r0.y = accv[1] + bs[cb + 1];
        r0.z = accv[2] + bs[cb + 2]; r0.w = accv[3] + bs[cb + 3];
        r1.x = accv[4] + bs[cb + 4]; r1.y = accv[5] + bs[cb + 5];
        r1.z = accv[6] + bs[cb + 6]; r1.w = accv[7] + bs[cb + 7];
        *(float4*)(zlog + (size_t)n * 32 + cb) = r0;
        *(float4*)(zlog + (size_t)n * 32 + cb + 4) = r1;
    }
}

// ---------------- launch ----------------

extern "C" void kernel_launch(void* const* d_in, const int* in_sizes, int n_in,
                              void* d_out, int out_size, void* d_ws, size_t ws_size,
                              hipStream_t stream) {
    const float* x   = (const float*)d_in[0];
    const int*   ei  = (const int*)d_in[1];
    const float* W1  = (const float*)d_in[2];
    const float* a1s = (const float*)d_in[3];
    const float* a1d = (const float*)d_in[4];
    const float* b1  = (const float*)d_in[5];
    const float* W2  = (const float*)d_in[6];
    const float* a2s = (const float*)d_in[7];
    const float* a2d = (const float*)d_in[8];
    const float* b2  = (const float*)d_in[9];
    const float* Wm  = (const float*)d_in[10];
    const float* ams = (const float*)d_in[11];
    const float* amd = (const float*)d_in[12];
    const float* bm  = (const float*)d_in[13];
    const float* Ws  = (const float*)d_in[14];
    const float* ass = (const float*)d_in[15];
    const float* asd = (const float*)d_in[16];
    const float* bs  = (const float*)d_in[17];

    float* out = (float*)d_out;
    float* zmean = out;                       // [50000,32]
    float* zlog  = out + 1600000;             // [50000,32]
    float* a_w1  = out + 3200000;             // [850000,4]
    float* a_w2  = out + 6600000;             // [850000,4]
    float* a_wm  = out + 10000000;            // [850000]
    float* a_ws_o = out + 10850000;           // [850000]

    float* ws = (float*)d_ws;
    size_t o = 0;
    f16*   Hh   = (f16*)(ws + o); o += (size_t)NN * 128;  // GEMM out [NN,256] f16, reused each layer
    f16*   h1h  = (f16*)(ws + o); o += (size_t)NN * 128;  // relu(h1) f16 (GEMM2 A)
    f16*   h2h  = (f16*)(ws + o); o += (size_t)NN * 32;   // h2 f16 [NN,64] (GEMM3 A)
    float* es1  = ws + o; o += NN * 4;
    float* es2  = ws + o; o += NN * 4;
    float* esms = ws + o; o += NN * 2;
    float* edi1 = ws + o; o += NN * 8;   // packed {ed[4], inv[4]} per node
    float* edi2 = ws + o; o += NN * 8;
    float* edims= ws + o; o += NN * 4;   // packed {ed[2], inv[2]}
    f16*   Wt1  = (f16*)(ws + o); o += 32768;      // [256][256] f16 transposed
    f16*   Wt2  = (f16*)(ws + o); o += 32768;
    f16*   Wtms = (f16*)(ws + o); o += 2048;       // [64][64] f16 transposed
    float* aSms = ws + o; o += 64;
    float* aDms = ws + o; o += 64;
    int* deg    = (int*)(ws + o); o += NN;
    int* offs   = (int*)(ws + o); o += NN;
    int* cursor = (int*)(ws + o); o += NN;
    u16* csrc   = (u16*)(ws + o); o += (ETOT + 1) / 2;   // u16 source ids (node < 50000 < 65536)

    const int edgeBlocks = (ETOT + 255) / 256;   // 3321
    const int nodeBlocks = (NN + 255) / 256;     // 196
    const int RB = (NN + 127) / 128;             // 391 gemm row-blocks
    const int tailY4 = (edgeBlocks + 3) / 4;     // tail rows for grid.x=4 gemms

    // ---- CSR deg (tail of packw) ----
    hipMemsetAsync(deg, 0, NN * sizeof(int), stream);
    packw_deg_kernel<<<256 + edgeBlocks, 256, 0, stream>>>(
        W1, W2, Wm, Ws, ams, ass, amd, asd, Wt1, Wt2, Wtms, aSms, aDms, ei, deg);

    // ---- CSR offs/cursor: wide 3-kernel scan ----
    scan1_kernel<<<nodeBlocks, 256, 0, stream>>>(deg, offs, cursor /*tmp bsum*/, NN);
    scan2_kernel<<<1, 256, 0, stream>>>(cursor, nodeBlocks);
    scan3_kernel<<<nodeBlocks, 256, 0, stream>>>(cursor, offs, deg /*reuse deg as cursor*/, NN);

    dim3 gg1(4, RB + tailY4);        // gemm1 + CSR fill tail
    dim3 gg2(4, RB + tailY4);        // gemm2 + layer-1 alpha tail
    dim3 gg3(1, RB + edgeBlocks);    // gemm3 + layer-2 alpha tail

    // ---- layer 1 (+ CSR fill overlapped; deg holds the cursor copy) ----
    mfma_gemm_fused<256, 4, true, 1><<<gg1, 256, 0, stream>>>(
        x, Wt1, Hh, a1s, a1d, es1, edi1, NN, 256, RB, ei, nullptr, nullptr, nullptr, deg, csrc);
    agg_concat_kernel<<<NN, 64, 0, stream>>>(Hh, es1, edi1, offs, csrc, b1, h1h);

    // ---- layer 2 (+ layer-1 alpha overlapped) ----
    mfma_gemm_fused<256, 4, false, 2><<<gg2, 256, 0, stream>>>(
        h1h, Wt2, Hh, a2s, a2d, es2, edi2, NN, 256, RB, ei, es1, edi1, a_w1, nullptr, nullptr);
    agg_mean_kernel<<<NN, 64, 0, stream>>>(Hh, es2, edi2, offs, csrc, b2, h2h);

    // ---- mean / log_std heads (+ layer-2 alpha overlapped) ----
    mfma_gemm_fused<64, 2, false, 2><<<gg3, 256, 0, stream>>>(
        h2h, Wtms, Hh, aSms, aDms, esms, edims, NN, 64, RB, ei, es2, edi2, a_w2, nullptr, nullptr);
    agg_ms_kernel<<<NN, 64, 0, stream>>>(Hh, esms, edims, offs, csrc, bm, bs, zmean, zlog);

    // ---- ms alpha outputs ----
    alpha_ms_kernel<<<edgeBlocks, 256, 0, stream>>>(ei, esms, edims, a_wm, a_ws_o);
}

// Round 13
// 460.915 us; speedup vs baseline: 1.0571x; 1.0571x over previous
//
#include <hip/hip_runtime.h>
#include <cstdint>
#include <cstddef>

#define NN 50000
#define EE 800000
#define ETOT 850000   // EE + NN self loops
#define NEG_SLOPE 0.2f

typedef _Float16 f16;
typedef __attribute__((ext_vector_type(8))) _Float16 f16x8;
typedef __attribute__((ext_vector_type(4))) float f32x4;
typedef unsigned short u16;

__device__ __forceinline__ float leaky(float v) { return v > 0.f ? v : NEG_SLOPE * v; }

// ---------------- CSR: 3-kernel wide scan ----------------

__global__ __launch_bounds__(256) void scan1_kernel(const int* __restrict__ deg, int* __restrict__ offs,
                                                    int* __restrict__ bsum, int n) {
    __shared__ int sh[256];
    int i = blockIdx.x * 256 + threadIdx.x;
    int v = (i < n) ? deg[i] : 0;
    sh[threadIdx.x] = v;
    __syncthreads();
    for (int off = 1; off < 256; off <<= 1) {
        int t = (threadIdx.x >= off) ? sh[threadIdx.x - off] : 0;
        __syncthreads();
        sh[threadIdx.x] += t;
        __syncthreads();
    }
    if (i < n) offs[i] = sh[threadIdx.x] - v;   // exclusive within block
    if (threadIdx.x == 255) bsum[blockIdx.x] = sh[255];
}

__global__ __launch_bounds__(256) void scan2_kernel(int* __restrict__ bsum, int nb) {
    __shared__ int sh[256];
    int v = (threadIdx.x < nb) ? bsum[threadIdx.x] : 0;
    sh[threadIdx.x] = v;
    __syncthreads();
    for (int off = 1; off < 256; off <<= 1) {
        int t = (threadIdx.x >= off) ? sh[threadIdx.x - off] : 0;
        __syncthreads();
        sh[threadIdx.x] += t;
        __syncthreads();
    }
    if (threadIdx.x < nb) bsum[threadIdx.x] = sh[threadIdx.x] - v;  // exclusive
}

__global__ __launch_bounds__(256) void scan3_kernel(const int* __restrict__ bsum, int* __restrict__ offs, int n) {
    int i = blockIdx.x * 256 + threadIdx.x;
    if (i < n) offs[i] += bsum[blockIdx.x];
}

// ---------------- pack weights (f16+transpose) + deg/rank tail ----------------
// The atomicAdd return value IS edge e's rank among its destination's edges;
// recording it here makes the CSR fill (gemm1 tail) atomic-free.

__global__ __launch_bounds__(256) void packw_deg_kernel(
    const float* __restrict__ W1, const float* __restrict__ W2,
    const float* __restrict__ Wm, const float* __restrict__ Ws,
    const float* __restrict__ ams, const float* __restrict__ ass,
    const float* __restrict__ amd, const float* __restrict__ asd,
    f16* __restrict__ Wt1, f16* __restrict__ Wt2, f16* __restrict__ Wtms,
    float* __restrict__ aS, float* __restrict__ aD,
    const int* __restrict__ ei, int* __restrict__ deg, u16* __restrict__ rank) {
    int b = blockIdx.x;
    if (b >= 256) {   // deg + rank tail
        int e = (b - 256) * 256 + threadIdx.x;
        if (e >= ETOT) return;
        int d = (e < EE) ? ei[EE + e] : (e - EE);
        int old = atomicAdd(&deg[d], 1);
        rank[e] = (u16)old;
        return;
    }
    int i = b * 256 + threadIdx.x;
    {
        int n = i >> 8, k = i & 255;   // Wt[n][k] = W[k][n]
        Wt1[(size_t)n * 256 + k] = (f16)W1[(size_t)k * 256 + n];
        Wt2[(size_t)n * 256 + k] = (f16)W2[(size_t)k * 256 + n];
    }
    if (i < 4096) {
        int c = i >> 6, k = i & 63;
        float v = (c < 32) ? Wm[k * 32 + c] : Ws[k * 32 + (c - 32)];
        Wtms[(size_t)c * 64 + k] = (f16)v;
    }
    if (i < 64) {
        aS[i] = (i < 32) ? ams[i] : ass[i - 32];
        aD[i] = (i < 32) ? amd[i] : asd[i - 32];
    }
}

// ---------------- MFMA GEMM + fused score dots + tail (fill or alpha) ----------------
// TAILMODE: 0 = none, 1 = atomic-free CSR fill (offs+rank), 2 = 4-head alpha writer.

template<int K, int NH, bool AF32, int TAILMODE>
__global__ __launch_bounds__(256) void mfma_gemm_fused(
    const void* __restrict__ Ap, const f16* __restrict__ Bt, f16* __restrict__ C,
    const float* __restrict__ aS, const float* __restrict__ aD,
    float* __restrict__ es, float* __restrict__ edi, int M, int N, int RB,
    const int* __restrict__ ei, const float* __restrict__ esA,
    const float* __restrict__ ediA, float* __restrict__ awA,
    const int* __restrict__ toffs, const u16* __restrict__ trank, u16* __restrict__ tcsrc) {
    if ((int)blockIdx.y >= RB) {
        int e = (((int)blockIdx.y - RB) * (int)gridDim.x + (int)blockIdx.x) * 256 + (int)threadIdx.x;
        if (e >= ETOT) return;
        int s, d;
        if (e < EE) { s = ei[e]; d = ei[EE + e]; } else { s = e - EE; d = e - EE; }
        if constexpr (TAILMODE == 1) {
            int p = toffs[d] + (int)trank[e];
            tcsrc[p] = (u16)s;
        } else if constexpr (TAILMODE == 2) {
            float4 esv = *(const float4*)(esA + (size_t)s * 4);
            float4 edv = *(const float4*)(ediA + (size_t)d * 8);
            float4 iv  = *(const float4*)(ediA + (size_t)d * 8 + 4);
            float4 r;
            r.x = __expf(leaky(esv.x + edv.x)) * iv.x;
            r.y = __expf(leaky(esv.y + edv.y)) * iv.y;
            r.z = __expf(leaky(esv.z + edv.z)) * iv.z;
            r.w = __expf(leaky(esv.w + edv.w)) * iv.w;
            *(float4*)(awA + (size_t)e * 4) = r;
        }
        return;
    }
    int w = threadIdx.x >> 6, lane = threadIdx.x & 63;
    int m0 = blockIdx.y * 128 + w * 32;
    int n0 = blockIdx.x * 64;
    int r = lane & 15, kb = lane >> 4;
    int ar0 = m0 + r;       if (ar0 > M - 1) ar0 = M - 1;
    int ar1 = m0 + 16 + r;  if (ar1 > M - 1) ar1 = M - 1;
    f32x4 acc[2][4] = {};
    const float* Af = (const float*)Ap;
    const f16*   Ah = (const f16*)Ap;
    size_t a0off = (size_t)ar0 * K + kb * 8;
    size_t a1off = (size_t)ar1 * K + kb * 8;
    const f16* bbase = Bt + (size_t)(n0 + r) * K + kb * 8;
    for (int k0 = 0; k0 < K; k0 += 32) {
        f16x8 a0, a1;
        if constexpr (AF32) {
            float4 l0 = *(const float4*)(Af + a0off + k0);
            float4 h0 = *(const float4*)(Af + a0off + k0 + 4);
            float4 l1 = *(const float4*)(Af + a1off + k0);
            float4 h1 = *(const float4*)(Af + a1off + k0 + 4);
            a0[0]=(f16)l0.x; a0[1]=(f16)l0.y; a0[2]=(f16)l0.z; a0[3]=(f16)l0.w;
            a0[4]=(f16)h0.x; a0[5]=(f16)h0.y; a0[6]=(f16)h0.z; a0[7]=(f16)h0.w;
            a1[0]=(f16)l1.x; a1[1]=(f16)l1.y; a1[2]=(f16)l1.z; a1[3]=(f16)l1.w;
            a1[4]=(f16)h1.x; a1[5]=(f16)h1.y; a1[6]=(f16)h1.z; a1[7]=(f16)h1.w;
        } else {
            a0 = *(const f16x8*)(Ah + a0off + k0);
            a1 = *(const f16x8*)(Ah + a1off + k0);
        }
#pragma unroll
        for (int ni = 0; ni < 4; ++ni) {
            f16x8 b = *(const f16x8*)(bbase + (size_t)ni * 16 * K + k0);
            acc[0][ni] = __builtin_amdgcn_mfma_f32_16x16x32_f16(a0, b, acc[0][ni], 0, 0, 0);
            acc[1][ni] = __builtin_amdgcn_mfma_f32_16x16x32_f16(a1, b, acc[1][ni], 0, 0, 0);
        }
    }
    float aSl[4], aDl[4];
#pragma unroll
    for (int ni = 0; ni < 4; ++ni) {
        aSl[ni] = aS[n0 + ni * 16 + r];
        aDl[ni] = aD[n0 + ni * 16 + r];
    }
#pragma unroll
    for (int mi = 0; mi < 2; ++mi) {
#pragma unroll
        for (int i = 0; i < 4; ++i) {
            int row = m0 + mi * 16 + kb * 4 + i;
            bool ok = row < M;
            if (ok) {
#pragma unroll
                for (int ni = 0; ni < 4; ++ni)
                    C[(size_t)row * N + n0 + ni * 16 + r] = (f16)acc[mi][ni][i];
            }
            if constexpr (NH == 4) {
                float pes = acc[mi][0][i] * aSl[0] + acc[mi][1][i] * aSl[1] + acc[mi][2][i] * aSl[2] + acc[mi][3][i] * aSl[3];
                float ped = acc[mi][0][i] * aDl[0] + acc[mi][1][i] * aDl[1] + acc[mi][2][i] * aDl[2] + acc[mi][3][i] * aDl[3];
#pragma unroll
                for (int off = 1; off < 16; off <<= 1) {
                    pes += __shfl_xor(pes, off);
                    ped += __shfl_xor(ped, off);
                }
                if (r == 0 && ok) {
                    es[(size_t)row * 4 + blockIdx.x] = pes;
                    edi[(size_t)row * 8 + blockIdx.x] = ped;
                }
            } else {
                float p0s = acc[mi][0][i] * aSl[0] + acc[mi][1][i] * aSl[1];
                float p1s = acc[mi][2][i] * aSl[2] + acc[mi][3][i] * aSl[3];
                float p0d = acc[mi][0][i] * aDl[0] + acc[mi][1][i] * aDl[1];
                float p1d = acc[mi][2][i] * aDl[2] + acc[mi][3][i] * aDl[3];
#pragma unroll
                for (int off = 1; off < 16; off <<= 1) {
                    p0s += __shfl_xor(p0s, off);
                    p1s += __shfl_xor(p1s, off);
                    p0d += __shfl_xor(p0d, off);
                    p1d += __shfl_xor(p1d, off);
                }
                if (r == 0 && ok) {
                    es[(size_t)row * 2 + 0] = p0s;
                    es[(size_t)row * 2 + 1] = p1s;
                    edi[(size_t)row * 4 + 0] = p0d;
                    edi[(size_t)row * 4 + 1] = p1d;
                }
            }
        }
    }
}

// ---------------- mean/log_std alpha writer ----------------

__global__ __launch_bounds__(256) void alpha_ms_kernel(const int* __restrict__ ei, const float* __restrict__ es,
                                                       const float* __restrict__ edi,
                                                       float* __restrict__ awm, float* __restrict__ aws) {
    int e = blockIdx.x * 256 + threadIdx.x;
    if (e >= ETOT) return;
    int s, d;
    if (e < EE) { s = ei[e]; d = ei[EE + e]; } else { s = e - EE; d = e - EE; }
    float2 esv = *(const float2*)(es + (size_t)s * 2);
    float2 edv = *(const float2*)(edi + (size_t)d * 4);
    float2 iv  = *(const float2*)(edi + (size_t)d * 4 + 2);
    awm[e] = __expf(leaky(esv.x + edv.x)) * iv.x;
    aws[e] = __expf(leaky(esv.y + edv.y)) * iv.y;
}

// ---------------- layer-1 aggregation: 1 node per 64-thread block ----------------

__global__ __launch_bounds__(64) void agg_concat_kernel(
    const f16* __restrict__ H, const float* __restrict__ es, float* __restrict__ edi,
    const int* __restrict__ offs, const u16* __restrict__ csrc,
    const float* __restrict__ bias, f16* __restrict__ out) {
    int lane = threadIdx.x;
    int n = blockIdx.x;
    int start = offs[n];
    int end = (n + 1 < NN) ? offs[n + 1] : ETOT;
    int deg = end - start;
    int h16 = lane >> 4, sub = lane & 15;
    float edh = edi[(size_t)n * 8 + h16];
    float dsum = 0.f;
    for (int j = sub; j < deg; j += 16) {
        int s = csrc[start + j];
        dsum += __expf(leaky(es[s * 4 + h16] + edh));
    }
    for (int off = 1; off < 16; off <<= 1) dsum += __shfl_xor(dsum, off);
    float inv = 1.f / (dsum + 1e-16f);
    if (sub == 0) edi[(size_t)n * 8 + 4 + h16] = inv;
    int half = lane >> 5;
    int l5 = lane & 31;
    int hh = l5 >> 3;
    int c8 = l5 * 8;
    float invh = __shfl(inv, hh << 4);
    float edhh = __shfl(edh, hh << 4);
    float accv[8] = {};
    int j = half;
    for (; j + 6 < deg; j += 8) {
        int p0 = start + j, p1 = start + j + 2, p2 = start + j + 4, p3 = start + j + 6;
        int s0 = csrc[p0], s1 = csrc[p1], s2 = csrc[p2], s3 = csrc[p3];
        float a0 = __expf(leaky(es[s0 * 4 + hh] + edhh)) * invh;
        float a1 = __expf(leaky(es[s1 * 4 + hh] + edhh)) * invh;
        float a2 = __expf(leaky(es[s2 * 4 + hh] + edhh)) * invh;
        float a3 = __expf(leaky(es[s3 * 4 + hh] + edhh)) * invh;
        f16x8 v0 = *(const f16x8*)(H + (size_t)s0 * 256 + c8);
        f16x8 v1 = *(const f16x8*)(H + (size_t)s1 * 256 + c8);
        f16x8 v2 = *(const f16x8*)(H + (size_t)s2 * 256 + c8);
        f16x8 v3 = *(const f16x8*)(H + (size_t)s3 * 256 + c8);
#pragma unroll
        for (int k = 0; k < 8; ++k)
            accv[k] += a0 * (float)v0[k] + a1 * (float)v1[k] + a2 * (float)v2[k] + a3 * (float)v3[k];
    }
    for (; j < deg; j += 2) {
        int s0 = csrc[start + j];
        float a0 = __expf(leaky(es[s0 * 4 + hh] + edhh)) * invh;
        f16x8 v0 = *(const f16x8*)(H + (size_t)s0 * 256 + c8);
#pragma unroll
        for (int k = 0; k < 8; ++k) accv[k] += a0 * (float)v0[k];
    }
#pragma unroll
    for (int k = 0; k < 8; ++k) accv[k] += __shfl_xor(accv[k], 32);
    if (lane < 32) {
        f16x8 r;
#pragma unroll
        for (int k = 0; k < 8; ++k) r[k] = (f16)fmaxf(accv[k] + bias[c8 + k], 0.f);
        *(f16x8*)(out + (size_t)n * 256 + c8) = r;
    }
}

// ---------------- layer-2 aggregation (mean over 4 heads) ----------------

__global__ __launch_bounds__(64) void agg_mean_kernel(
    const f16* __restrict__ H, const float* __restrict__ es, float* __restrict__ edi,
    const int* __restrict__ offs, const u16* __restrict__ csrc,
    const float* __restrict__ bias, f16* __restrict__ out) {
    int lane = threadIdx.x;
    int n = blockIdx.x;
    int start = offs[n];
    int end = (n + 1 < NN) ? offs[n + 1] : ETOT;
    int deg = end - start;
    int h16 = lane >> 4, sub = lane & 15;
    float edh = edi[(size_t)n * 8 + h16];
    float dsum = 0.f;
    for (int j = sub; j < deg; j += 16) {
        int s = csrc[start + j];
        dsum += __expf(leaky(es[s * 4 + h16] + edh));
    }
    for (int off = 1; off < 16; off <<= 1) dsum += __shfl_xor(dsum, off);
    float inv = 1.f / (dsum + 1e-16f);
    if (sub == 0) edi[(size_t)n * 8 + 4 + h16] = inv;
    int half = lane >> 5;
    int l5 = lane & 31;
    int hh = l5 >> 3;
    int c8 = l5 * 8;
    float invh = __shfl(inv, hh << 4);
    float edhh = __shfl(edh, hh << 4);
    float accv[8] = {};
    int j = half;
    for (; j + 6 < deg; j += 8) {
        int p0 = start + j, p1 = start + j + 2, p2 = start + j + 4, p3 = start + j + 6;
        int s0 = csrc[p0], s1 = csrc[p1], s2 = csrc[p2], s3 = csrc[p3];
        float a0 = __expf(leaky(es[s0 * 4 + hh] + edhh)) * invh;
        float a1 = __expf(leaky(es[s1 * 4 + hh] + edhh)) * invh;
        float a2 = __expf(leaky(es[s2 * 4 + hh] + edhh)) * invh;
        float a3 = __expf(leaky(es[s3 * 4 + hh] + edhh)) * invh;
        f16x8 v0 = *(const f16x8*)(H + (size_t)s0 * 256 + c8);
        f16x8 v1 = *(const f16x8*)(H + (size_t)s1 * 256 + c8);
        f16x8 v2 = *(const f16x8*)(H + (size_t)s2 * 256 + c8);
        f16x8 v3 = *(const f16x8*)(H + (size_t)s3 * 256 + c8);
#pragma unroll
        for (int k = 0; k < 8; ++k)
            accv[k] += a0 * (float)v0[k] + a1 * (float)v1[k] + a2 * (float)v2[k] + a3 * (float)v3[k];
    }
    for (; j < deg; j += 2) {
        int s0 = csrc[start + j];
        float a0 = __expf(leaky(es[s0 * 4 + hh] + edhh)) * invh;
        f16x8 v0 = *(const f16x8*)(H + (size_t)s0 * 256 + c8);
#pragma unroll
        for (int k = 0; k < 8; ++k) accv[k] += a0 * (float)v0[k];
    }
#pragma unroll
    for (int k = 0; k < 8; ++k) {
        accv[k] += __shfl_xor(accv[k], 8);
        accv[k] += __shfl_xor(accv[k], 16);
        accv[k] += __shfl_xor(accv[k], 32);
    }
    if (lane < 8) {
        f16x8 r;
#pragma unroll
        for (int k = 0; k < 8; ++k) r[k] = (f16)fmaxf(accv[k] * 0.25f + bias[lane * 8 + k], 0.f);
        *(f16x8*)(out + (size_t)n * 64 + lane * 8) = r;
    }
}

// ---------------- mean/log_std heads aggregation ----------------

__global__ __launch_bounds__(64) void agg_ms_kernel(
    const f16* __restrict__ H, const float* __restrict__ es, float* __restrict__ edi,
    const int* __restrict__ offs, const u16* __restrict__ csrc,
    const float* __restrict__ bm, const float* __restrict__ bs,
    float* __restrict__ zmean, float* __restrict__ zlog) {
    int lane = threadIdx.x;
    int n = blockIdx.x;
    int start = offs[n];
    int end = (n + 1 < NN) ? offs[n + 1] : ETOT;
    int deg = end - start;
    int g = lane >> 5, sub = lane & 31;
    float edg = edi[(size_t)n * 4 + g];
    float dsum = 0.f;
    for (int j = sub; j < deg; j += 32) {
        int s = csrc[start + j];
        dsum += __expf(leaky(es[s * 2 + g] + edg));
    }
    for (int off = 1; off < 32; off <<= 1) dsum += __shfl_xor(dsum, off);
    float inv = 1.f / (dsum + 1e-16f);
    if (sub == 0) edi[(size_t)n * 4 + 2 + g] = inv;
    int slot = lane >> 3;
    int le = lane & 7;
    int g2 = le >> 2;
    int c8 = le * 8;
    float invg = __shfl(inv, g2 << 5);
    float edg2 = __shfl(edg, g2 << 5);
    float accv[8] = {};
    for (int j = slot; j < deg; j += 8) {
        int p = start + j;
        int s = csrc[p];
        float a = __expf(leaky(es[s * 2 + g2] + edg2)) * invg;
        f16x8 v = *(const f16x8*)(H + (size_t)s * 64 + c8);
#pragma unroll
        for (int k = 0; k < 8; ++k) accv[k] += a * (float)v[k];
    }
#pragma unroll
    for (int k = 0; k < 8; ++k) {
        accv[k] += __shfl_xor(accv[k], 8);
        accv[k] += __shfl_xor(accv[k], 16);
        accv[k] += __shfl_xor(accv[k], 32);
    }
    if (lane < 4) {
        float4 r0, r1;
        int cb = lane * 8;
        r0.x = accv[0] + bm[cb + 0]; r0.y = accv[1] + bm[cb + 1];
        r0.z = accv[2] + bm[cb + 2]; r0.w = accv[3] + bm[cb + 3];
        r1.x = accv[4] + bm[cb + 4]; r1.y = accv[5] + bm[cb + 5];
        r1.z = accv[6] + bm[cb + 6]; r1.w = accv[7] + bm[cb + 7];
        *(float4*)(zmean + (size_t)n * 32 + cb) = r0;
        *(float4*)(zmean + (size_t)n * 32 + cb + 4) = r1;
    } else if (lane < 8) {
        float4 r0, r1;
        int cb = (lane - 4) * 8;
        r0.x = accv[0] + bs[cb + 0]; r0.y = accv[1] + bs[cb + 1];
        r0.z = accv[2] + bs[cb + 2]; r0.w = accv[3] + bs[cb + 3];
        r1.x = accv[4] + bs[cb + 4]; r1.y = accv[5] + bs[cb + 5];
        r1.z = accv[6] + bs[cb + 6]; r1.w = accv[7] + bs[cb + 7];
        *(float4*)(zlog + (size_t)n * 32 + cb) = r0;
        *(float4*)(zlog + (size_t)n * 32 + cb + 4) = r1;
    }
}

// ---------------- launch ----------------

extern "C" void kernel_launch(void* const* d_in, const int* in_sizes, int n_in,
                              void* d_out, int out_size, void* d_ws, size_t ws_size,
                              hipStream_t stream) {
    const float* x   = (const float*)d_in[0];
    const int*   ei  = (const int*)d_in[1];
    const float* W1  = (const float*)d_in[2];
    const float* a1s = (const float*)d_in[3];
    const float* a1d = (const float*)d_in[4];
    const float* b1  = (const float*)d_in[5];
    const float* W2  = (const float*)d_in[6];
    const float* a2s = (const float*)d_in[7];
    const float* a2d = (const float*)d_in[8];
    const float* b2  = (const float*)d_in[9];
    const float* Wm  = (const float*)d_in[10];
    const float* ams = (const float*)d_in[11];
    const float* amd = (const float*)d_in[12];
    const float* bm  = (const float*)d_in[13];
    const float* Ws  = (const float*)d_in[14];
    const float* ass = (const float*)d_in[15];
    const float* asd = (const float*)d_in[16];
    const float* bs  = (const float*)d_in[17];

    float* out = (float*)d_out;
    float* zmean = out;                       // [50000,32]
    float* zlog  = out + 1600000;             // [50000,32]
    float* a_w1  = out + 3200000;             // [850000,4]
    float* a_w2  = out + 6600000;             // [850000,4]
    float* a_wm  = out + 10000000;            // [850000]
    float* a_ws_o = out + 10850000;           // [850000]

    float* ws = (float*)d_ws;
    size_t o = 0;
    f16*   Hh   = (f16*)(ws + o); o += (size_t)NN * 128;  // GEMM out [NN,256] f16, reused each layer
    f16*   h1h  = (f16*)(ws + o); o += (size_t)NN * 128;  // relu(h1) f16 (GEMM2 A)
    f16*   h2h  = (f16*)(ws + o); o += (size_t)NN * 32;   // h2 f16 [NN,64] (GEMM3 A)
    float* es1  = ws + o; o += NN * 4;
    float* es2  = ws + o; o += NN * 4;
    float* esms = ws + o; o += NN * 2;
    float* edi1 = ws + o; o += NN * 8;   // packed {ed[4], inv[4]} per node
    float* edi2 = ws + o; o += NN * 8;
    float* edims= ws + o; o += NN * 4;   // packed {ed[2], inv[2]}
    f16*   Wt1  = (f16*)(ws + o); o += 32768;      // [256][256] f16 transposed
    f16*   Wt2  = (f16*)(ws + o); o += 32768;
    f16*   Wtms = (f16*)(ws + o); o += 2048;       // [64][64] f16 transposed
    float* aSms = ws + o; o += 64;
    float* aDms = ws + o; o += 64;
    int* deg    = (int*)(ws + o); o += NN;
    int* offs   = (int*)(ws + o); o += NN;
    int* bsum   = (int*)(ws + o); o += NN;       // scan block sums
    u16* rank   = (u16*)(ws + o); o += (ETOT + 1) / 2;   // per-edge rank among its dst's edges
    u16* csrc   = (u16*)(ws + o); o += (ETOT + 1) / 2;   // u16 source ids

    const int edgeBlocks = (ETOT + 255) / 256;   // 3321
    const int nodeBlocks = (NN + 255) / 256;     // 196
    const int RB = (NN + 127) / 128;             // 391 gemm row-blocks
    const int tailY4 = (edgeBlocks + 3) / 4;     // tail rows for grid.x=4 gemms

    // ---- CSR deg + per-edge rank (tail of packw) ----
    hipMemsetAsync(deg, 0, NN * sizeof(int), stream);
    packw_deg_kernel<<<256 + edgeBlocks, 256, 0, stream>>>(
        W1, W2, Wm, Ws, ams, ass, amd, asd, Wt1, Wt2, Wtms, aSms, aDms, ei, deg, rank);

    // ---- CSR offs: wide 3-kernel scan ----
    scan1_kernel<<<nodeBlocks, 256, 0, stream>>>(deg, offs, bsum, NN);
    scan2_kernel<<<1, 256, 0, stream>>>(bsum, nodeBlocks);
    scan3_kernel<<<nodeBlocks, 256, 0, stream>>>(bsum, offs, NN);

    dim3 gg1(4, RB + tailY4);        // gemm1 + atomic-free CSR fill tail
    dim3 gg2(4, RB + tailY4);        // gemm2 + layer-1 alpha tail
    dim3 gg3(1, RB + edgeBlocks);    // gemm3 + layer-2 alpha tail

    // ---- layer 1 (+ CSR fill overlapped, no atomics) ----
    mfma_gemm_fused<256, 4, true, 1><<<gg1, 256, 0, stream>>>(
        x, Wt1, Hh, a1s, a1d, es1, edi1, NN, 256, RB, ei, nullptr, nullptr, nullptr, offs, rank, csrc);
    agg_concat_kernel<<<NN, 64, 0, stream>>>(Hh, es1, edi1, offs, csrc, b1, h1h);

    // ---- layer 2 (+ layer-1 alpha overlapped) ----
    mfma_gemm_fused<256, 4, false, 2><<<gg2, 256, 0, stream>>>(
        h1h, Wt2, Hh, a2s, a2d, es2, edi2, NN, 256, RB, ei, es1, edi1, a_w1, nullptr, nullptr, nullptr);
    agg_mean_kernel<<<NN, 64, 0, stream>>>(Hh, es2, edi2, offs, csrc, b2, h2h);

    // ---- mean / log_std heads (+ layer-2 alpha overlapped) ----
    mfma_gemm_fused<64, 2, false, 2><<<gg3, 256, 0, stream>>>(
        h2h, Wtms, Hh, aSms, aDms, esms, edims, NN, 64, RB, ei, es2, edi2, a_w2, nullptr, nullptr, nullptr);
    agg_ms_kernel<<<NN, 64, 0, stream>>>(Hh, esms, edims, offs, csrc, bm, bs, zmean, zlog);

    // ---- ms alpha outputs ----
    alpha_ms_kernel<<<edgeBlocks, 256, 0, stream>>>(ei, esms, edims, a_wm, a_ws_o);
}